// Round 13
// baseline (776.740 us; speedup 1.0000x reference)
//
#include <hip/hip_runtime.h>
#include <stdint.h>
#include <stddef.h>

// ISNNet: x[:,0]=x0; x[:,t] = x[:,t-1] @ eW.T + I[:,t-1] @ W_inv_eW.T
// B=64, T=2048, D=256.  3-term compensated bf16 MFMA throughout.
// Round 13: scan -> 8-wave WGs (32 cols/wave, half the LDS broadcast) with
// CHUNK=16 and 512 WGs = 2 WGs/CU (cross-WG overlap); J=3 boundary
// (M1=A^16, M2=A^32, M3=A^48 — truncation at A^64, same as verified r9).

#define BATCH 64
#define TLEN 2048
#define DDIM 256
#define CHUNK 16
#define NCHUNK 128

typedef __attribute__((ext_vector_type(8))) short short8;
typedef __attribute__((ext_vector_type(4))) float f32x4;
typedef __attribute__((ext_vector_type(16))) float f32x16;

#define MFMA16(a, b, c) __builtin_amdgcn_mfma_f32_16x16x32_bf16((a), (b), (c), 0, 0, 0)
#define MFMA32(a, b, c) __builtin_amdgcn_mfma_f32_32x32x16_bf16((a), (b), (c), 0, 0, 0)
#define PIN8(x) asm volatile("" : "+v"(x))

__device__ __forceinline__ uint16_t f2bf(float f) {
  union { float f; uint32_t u; } v; v.f = f;
  return (uint16_t)((v.u + 0x7fffu + ((v.u >> 16) & 1u)) >> 16);  // RNE
}
__device__ __forceinline__ float bf2f(uint16_t h) {
  union { uint32_t u; float f; } v; v.u = ((uint32_t)h) << 16;
  return v.f;
}

__device__ __forceinline__ void split8(const float* fv, short8& hi, short8& lo) {
#pragma unroll
  for (int j = 0; j < 8; ++j) {
    uint16_t hb = f2bf(fv[j]);
    hi[j] = (short)hb;
    lo[j] = (short)f2bf(fv[j] - bf2f(hb));
  }
}

// 16-row swizzle (scan state tiles)
__device__ __forceinline__ uint32_t swz(int row) {
  return ((uint32_t)((row & 7) << 4)) ^ ((uint32_t)(((row >> 3) & 1) << 7));
}
// 32-row swizzle (k_u I-tiles)
__device__ __forceinline__ uint32_t swz32(int row) {
  return ((uint32_t)((row & 7) << 4)) ^ ((uint32_t)(((row >> 3) & 3) << 7));
}

// raw barrier: waits LDS ops but NOT outstanding global loads
__device__ __forceinline__ void wg_barrier() {
  __builtin_amdgcn_sched_barrier(0);
  asm volatile("s_waitcnt lgkmcnt(0)" ::: "memory");
  __builtin_amdgcn_s_barrier();
  asm volatile("" ::: "memory");
  __builtin_amdgcn_sched_barrier(0);
}

// ---------------- workspace layout (bytes) ----------------
#define WS_M1F    (0)            // f32 [256][256]
#define WS_M1_HI  (256 * 1024)
#define WS_M1_LO  (384 * 1024)
#define WS_M2F    (512 * 1024)
#define WS_M2_HI  (768 * 1024)
#define WS_M2_LO  (896 * 1024)
#define WS_M3F    (1024 * 1024)
#define WS_M3_HI  (1280 * 1024)
#define WS_M3_LO  (1408 * 1024)
#define WS_S      (2560 * 1024)  // f32 [128][64][256] = 8MB

// ---------------- k_u: u = I @ Wi^T -> d_out at time t+1 (32x32x16 MFMA) ----
// 8 waves x (32 rows x 32 cols); 256 WGs x 16 tiles of 32 t-rows; LDS dbuf.
__global__ __launch_bounds__(512, 1) void k_u(const float* __restrict__ I,
                                              const float* __restrict__ Wi,
                                              float* __restrict__ out) {
  const int tid = threadIdx.x;
  const int w = tid >> 6, l = tid & 63, l31 = l & 31, half = l >> 5;
  const int ns = w * 32;  // 32 cols per wave
  __shared__ __align__(16) uint16_t sIh[2][8192];  // 32 x 256 bf16, swizzled
  __shared__ __align__(16) uint16_t sIl[2][8192];

  // Wb fragments: col = ns+l31, k = ks*16 + half*8 .. +8  (128 regs, pinned)
  short8 bh[16], bl[16];
#pragma unroll
  for (int ks = 0; ks < 16; ++ks) {
    const float* wp = Wi + (size_t)(ns + l31) * 256 + ks * 16 + half * 8;
    f32x4 f0 = *reinterpret_cast<const f32x4*>(wp);
    f32x4 f1 = *reinterpret_cast<const f32x4*>(wp + 4);
    float fv[8] = {f0[0], f0[1], f0[2], f0[3], f1[0], f1[1], f1[2], f1[3]};
    split8(fv, bh[ks], bl[ks]);
    PIN8(bh[ks]);
    PIN8(bl[ks]);
  }

  const int srow = tid >> 4;        // 0..31 (staging row)
  const int sc0 = (tid & 15) * 16;  // 0..240 (staging col base, 16 f32)
  const uint32_t wb0 = ((uint32_t)(srow * 512 + sc0 * 2)) ^ swz32(srow);
  const uint32_t wb1 = ((uint32_t)(srow * 512 + sc0 * 2 + 16)) ^ swz32(srow);

  const int b0 = blockIdx.x >> 6;
  const int tt = blockIdx.x & 63;
  const bool edge = (tt == 63);          // only edge WGs can hit trow > 2046
  const size_t S4 = (size_t)4 * TLEN * DDIM;  // per-it stride
  const float* Ip = I + ((size_t)b0 * TLEN + tt * 32 + srow) * DDIM + sc0;
  float* Op = out + ((size_t)b0 * TLEN + tt * 32 + 1) * DDIM + ns + l31;

  uint32_t ro[16];
#pragma unroll
  for (int ks = 0; ks < 16; ++ks)
    ro[ks] = ((uint32_t)(l31 * 512 + ks * 32 + half * 16)) ^ swz32(l31);
  int rowoff[16];
#pragma unroll
  for (int r = 0; r < 16; ++r)
    rowoff[r] = ((r & 3) + 8 * (r >> 2) + 4 * half) * DDIM;

  f32x4 ra[4], rb[4];
  auto loadI = [&](int it, f32x4 (&dst)[4]) {
    const float* src = Ip + (size_t)it * S4;
#pragma unroll
    for (int j = 0; j < 4; ++j)
      dst[j] = *reinterpret_cast<const f32x4*>(src + j * 4);
  };

  auto do_tile = [&](int it, f32x4 (&cur)[4], int q, bool pre) {
    short8 hi[2], lo[2];
#pragma unroll
    for (int h2 = 0; h2 < 2; ++h2) {
      float fv[8] = {cur[h2 * 2][0], cur[h2 * 2][1], cur[h2 * 2][2], cur[h2 * 2][3],
                     cur[h2 * 2 + 1][0], cur[h2 * 2 + 1][1], cur[h2 * 2 + 1][2], cur[h2 * 2 + 1][3]};
      split8(fv, hi[h2], lo[h2]);
    }
    if (pre) loadI(it + 2, cur);     // reload same buffer for tile it+2
    *reinterpret_cast<short8*>(reinterpret_cast<char*>(sIh[q]) + wb0) = hi[0];
    *reinterpret_cast<short8*>(reinterpret_cast<char*>(sIh[q]) + wb1) = hi[1];
    *reinterpret_cast<short8*>(reinterpret_cast<char*>(sIl[q]) + wb0) = lo[0];
    *reinterpret_cast<short8*>(reinterpret_cast<char*>(sIl[q]) + wb1) = lo[1];
    wg_barrier();                    // writes of buf q visible; buf q^1 free
    f32x16 acc;
#pragma unroll
    for (int j = 0; j < 16; ++j) acc[j] = 0.f;
    __builtin_amdgcn_s_setprio(1);
#pragma unroll
    for (int ks = 0; ks < 16; ++ks) {
      short8 ih = *reinterpret_cast<const short8*>((const char*)sIh[q] + ro[ks]);
      short8 il = *reinterpret_cast<const short8*>((const char*)sIl[q] + ro[ks]);
      acc = MFMA32(ih, bh[ks], acc);
      acc = MFMA32(il, bh[ks], acc);
      acc = MFMA32(ih, bl[ks], acc);
    }
    __builtin_amdgcn_s_setprio(0);
    float* ob = Op + (size_t)it * S4;
    if (!edge) {
#pragma unroll
      for (int r = 0; r < 16; ++r) ob[rowoff[r]] = acc[r];
    } else {
#pragma unroll
      for (int r = 0; r < 16; ++r)
        if (rowoff[r] < 31 * DDIM) ob[rowoff[r]] = acc[r];  // skip trow 2047
    }
  };

  loadI(0, ra);
  loadI(1, rb);
#pragma unroll 1
  for (int it = 0; it < 16; it += 2) {
    do_tile(it, ra, 0, it + 2 < 16);
    do_tile(it + 1, rb, 1, it + 3 < 16);
  }
}

// ---------------- k_scan: in-chunk recurrence (CHUNK=16), 8-wave WGs --------
// 512 WGs (128 chunks x 4 rg) = 2 WGs/CU. Wave owns 32 cols (nf=2 frags).
// pass 2 init computes Y_c = T_c + T_{c-1}@M1 + T_{c-2}@M2 + T_{c-3}@M3.
__global__ __launch_bounds__(512, 4) void k_scan(const int pass,
                                                 const float* __restrict__ eW,
                                                 float* __restrict__ xu,  // d_out: u in (shifted), x out
                                                 const float* __restrict__ x0,
                                                 float* __restrict__ S,
                                                 const uint16_t* __restrict__ M1h,
                                                 const uint16_t* __restrict__ M1l,
                                                 const uint16_t* __restrict__ M2h,
                                                 const uint16_t* __restrict__ M2l,
                                                 const uint16_t* __restrict__ M3h,
                                                 const uint16_t* __restrict__ M3l) {
  const int tid = threadIdx.x;
  const int w = tid >> 6, l = tid & 63, l15 = l & 15, quad = l >> 4;
  const int ns = w * 32;  // 32 cols per wave
  const int c = blockIdx.x >> 2;   // 0..127
  const int rg = blockIdx.x & 3;
  __shared__ __align__(16) uint16_t sh[2][4096];
  __shared__ __align__(16) uint16_t sl[2][4096];

  const int t0 = c * CHUNK;
  const int nsteps = (t0 + CHUNK <= TLEN - 1) ? CHUNK : (TLEN - 1 - t0);

  float u0[8], u1[8], u2[8], u3[8], fin[8];
#pragma unroll
  for (int j = 0; j < 8; ++j) { u0[j] = 0.f; u1[j] = 0.f; u2[j] = 0.f; u3[j] = 0.f; fin[j] = 0.f; }

  auto issue_u = [&](int i, float (&dst)[8]) {
    if (i > nsteps) return;
#pragma unroll
    for (int nf = 0; nf < 2; ++nf)
#pragma unroll
      for (int r = 0; r < 4; ++r) {
        int b = rg * 16 + quad * 4 + r;
        dst[nf * 4 + r] = xu[((size_t)b * TLEN + t0 + i) * DDIM + ns + nf * 16 + l15];
      }
  };
  // fire the first 4 steps' u loads before anything else
  issue_u(1, u0);
  issue_u(2, u1);
  issue_u(3, u2);
  issue_u(4, u3);

  // A fragments: per-wave 32-col slice (nf=2), split from f32 eW, pinned
  short8 fAh[2][8], fAl[2][8];
#pragma unroll
  for (int nf = 0; nf < 2; ++nf)
#pragma unroll
    for (int ks = 0; ks < 8; ++ks) {
      const float* ap = eW + (size_t)(ns + nf * 16 + l15) * 256 + ks * 32 + quad * 8;
      f32x4 f0 = *reinterpret_cast<const f32x4*>(ap);
      f32x4 f1 = *reinterpret_cast<const f32x4*>(ap + 4);
      float fv[8] = {f0[0], f0[1], f0[2], f0[3], f1[0], f1[1], f1[2], f1[3]};
      split8(fv, fAh[nf][ks], fAl[nf][ks]);
      PIN8(fAh[nf][ks]);
      PIN8(fAl[nf][ks]);
    }

  // init state (buf 0)
  if (pass == 1) {
    for (int i = tid; i < 4096; i += 512) {
      int row = i >> 8, k = i & 255;
      uint32_t byte = ((uint32_t)(row * 512 + k * 2)) ^ swz(row);
      *(uint16_t*)((char*)sh[0] + byte) = 0;
      *(uint16_t*)((char*)sl[0] + byte) = 0;
    }
  } else {
    // fused bnd: Y = T_c + T_{c-1}@M1 + T_{c-2}@M2 + T_{c-3}@M3
    f32x4 yacc[2];
    {
      const float* Tc = (c == 0) ? x0 : (S + (size_t)(c - 1) * 64 * 256);
#pragma unroll
      for (int nf = 0; nf < 2; ++nf)
#pragma unroll
        for (int r = 0; r < 4; ++r)
          yacc[nf][r] = Tc[(size_t)(rg * 16 + quad * 4 + r) * 256 + ns + nf * 16 + l15];
    }
#pragma unroll 1
    for (int j = 1; j <= 3; ++j) {
      int k = c - j;
      if (k < 0) break;
      const float* Tp = (k == 0) ? x0 : (S + (size_t)(k - 1) * 64 * 256);
      const uint16_t* Bh = (j == 1) ? M1h : (j == 2) ? M2h : M3h;
      const uint16_t* Bl = (j == 1) ? M1l : (j == 2) ? M2l : M3l;
#pragma unroll
      for (int ks = 0; ks < 8; ++ks) {
        const float* ap = Tp + (size_t)(rg * 16 + l15) * 256 + ks * 32 + quad * 8;
        f32x4 f0 = *reinterpret_cast<const f32x4*>(ap);
        f32x4 f1 = *reinterpret_cast<const f32x4*>(ap + 4);
        float fv[8] = {f0[0], f0[1], f0[2], f0[3], f1[0], f1[1], f1[2], f1[3]};
        short8 ah, al8;
        split8(fv, ah, al8);
#pragma unroll
        for (int nf = 0; nf < 2; ++nf) {
          const int off = (ns + nf * 16 + l15) * 256 + ks * 32 + quad * 8;
          short8 bhf = *reinterpret_cast<const short8*>(Bh + off);
          short8 blf = *reinterpret_cast<const short8*>(Bl + off);
          yacc[nf] = MFMA16(ah, bhf, yacc[nf]);
          yacc[nf] = MFMA16(al8, bhf, yacc[nf]);
          yacc[nf] = MFMA16(ah, blf, yacc[nf]);
        }
      }
    }
#pragma unroll
    for (int nf = 0; nf < 2; ++nf)
#pragma unroll
      for (int r = 0; r < 4; ++r) {
        int row = quad * 4 + r, col = ns + nf * 16 + l15;
        float v = yacc[nf][r];
        if (c == 0) xu[((size_t)(rg * 16 + row) * TLEN) * DDIM + col] = v;  // x[:,0,:]
        uint16_t hb = f2bf(v);
        uint16_t lb = f2bf(v - bf2f(hb));
        uint32_t byte = ((uint32_t)(row * 512 + col * 2)) ^ swz(row);
        *(uint16_t*)((char*)sh[0] + byte) = hb;
        *(uint16_t*)((char*)sl[0] + byte) = lb;
      }
  }
  wg_barrier();  // no vmcnt drain: u prefetches stay in flight

  int p = 0;
  auto step = [&](int i, float (&ucur)[8]) {
    f32x4 acc0 = {0.f, 0.f, 0.f, 0.f}, acc1 = {0.f, 0.f, 0.f, 0.f};
    __builtin_amdgcn_s_setprio(1);
#pragma unroll
    for (int ks = 0; ks < 8; ++ks) {
      uint32_t byte = ((uint32_t)(l15 * 512 + ks * 64 + quad * 16)) ^ swz(l15);
      short8 xh = *reinterpret_cast<const short8*>((const char*)sh[p] + byte);
      short8 xl = *reinterpret_cast<const short8*>((const char*)sl[p] + byte);
      acc0 = MFMA16(xh, fAh[0][ks], acc0);
      acc0 = MFMA16(xl, fAh[0][ks], acc0);
      acc0 = MFMA16(xh, fAl[0][ks], acc0);
      acc1 = MFMA16(xh, fAh[1][ks], acc1);
      acc1 = MFMA16(xl, fAh[1][ks], acc1);
      acc1 = MFMA16(xh, fAl[1][ks], acc1);
    }
    __builtin_amdgcn_s_setprio(0);
#pragma unroll
    for (int nf = 0; nf < 2; ++nf)
#pragma unroll
      for (int r = 0; r < 4; ++r)
        fin[nf * 4 + r] = (nf ? acc1[r] : acc0[r]) + ucur[nf * 4 + r];
    issue_u(i + 4, ucur);  // refill this buffer for step i+4
    if (pass == 2) {
#pragma unroll
      for (int nf = 0; nf < 2; ++nf)
#pragma unroll
        for (int r = 0; r < 4; ++r) {
          int b = rg * 16 + quad * 4 + r;
          xu[((size_t)b * TLEN + t0 + i) * DDIM + ns + nf * 16 + l15] = fin[nf * 4 + r];
        }
    }
    if (i < nsteps) {
#pragma unroll
      for (int nf = 0; nf < 2; ++nf)
#pragma unroll
        for (int r = 0; r < 4; ++r) {
          int row = quad * 4 + r, col = ns + nf * 16 + l15;
          float v = fin[nf * 4 + r];
          uint16_t hb = f2bf(v);
          uint16_t lb = f2bf(v - bf2f(hb));
          uint32_t byte = ((uint32_t)(row * 512 + col * 2)) ^ swz(row);
          *(uint16_t*)((char*)sh[p ^ 1] + byte) = hb;
          *(uint16_t*)((char*)sl[p ^ 1] + byte) = lb;
        }
      wg_barrier();
      p ^= 1;
    }
  };

  int i = 1;
  for (; i + 3 <= nsteps; i += 4) {
    step(i, u0);
    step(i + 1, u1);
    step(i + 2, u2);
    step(i + 3, u3);
  }
  if (i <= nsteps) { step(i, u0); ++i; }
  if (i <= nsteps) { step(i, u1); ++i; }
  if (i <= nsteps) { step(i, u2); ++i; }

  if (pass == 1) {
#pragma unroll
    for (int nf = 0; nf < 2; ++nf)
#pragma unroll
      for (int r = 0; r < 4; ++r) {
        int row = quad * 4 + r, col = ns + nf * 16 + l15;
        S[((size_t)c * 64 + rg * 16 + row) * DDIM + col] = fin[nf * 4 + r];
      }
  }
}

// ---------------- k_mm256A: OUT = Abar @ Abar from raw eW (stage 1) ----------
__global__ __launch_bounds__(512) void k_mm256A(const float* __restrict__ eW,
                                                float* __restrict__ Of,
                                                uint16_t* __restrict__ Oh,
                                                uint16_t* __restrict__ Ol) {
  const int mf = blockIdx.x;  // 0..15
  const int tid = threadIdx.x;
  const int w = tid >> 6, l = tid & 63, l15 = l & 15, quad = l >> 4;
  const int ns = w * 32;
  f32x4 acc[2];
  acc[0] = {0.f, 0.f, 0.f, 0.f};
  acc[1] = {0.f, 0.f, 0.f, 0.f};

#pragma unroll
  for (int ks = 0; ks < 8; ++ks) {
    float fv[8];
#pragma unroll
    for (int j = 0; j < 8; ++j)
      fv[j] = eW[(size_t)(ks * 32 + quad * 8 + j) * 256 + mf * 16 + l15];
    short8 ah, al8;
    split8(fv, ah, al8);
#pragma unroll
    for (int nf = 0; nf < 2; ++nf) {
      const float* bp = eW + (size_t)(ns + nf * 16 + l15) * 256 + ks * 32 + quad * 8;
      f32x4 b0 = *reinterpret_cast<const f32x4*>(bp);
      f32x4 b1 = *reinterpret_cast<const f32x4*>(bp + 4);
      float bv[8] = {b0[0], b0[1], b0[2], b0[3], b1[0], b1[1], b1[2], b1[3]};
      short8 bhf, blf;
      split8(bv, bhf, blf);
      acc[nf] = MFMA16(ah, bhf, acc[nf]);
      acc[nf] = MFMA16(al8, bhf, acc[nf]);
      acc[nf] = MFMA16(ah, blf, acc[nf]);
    }
  }
#pragma unroll
  for (int nf = 0; nf < 2; ++nf)
#pragma unroll
    for (int r = 0; r < 4; ++r) {
      int row = mf * 16 + quad * 4 + r;
      int col = ns + nf * 16 + l15;
      float v = acc[nf][r];
      Of[(size_t)row * 256 + col] = v;
      uint16_t hb = f2bf(v);
      Oh[(size_t)col * 256 + row] = hb;
      Ol[(size_t)col * 256 + row] = f2bf(v - bf2f(hb));
    }
}

// ---------------- k_mm256: OUT = Af @ B, 16 WGs (stages 2+) ----------------
__global__ __launch_bounds__(512) void k_mm256(const float* __restrict__ Af,
                                               const uint16_t* __restrict__ Bh,
                                               const uint16_t* __restrict__ Bl,
                                               float* __restrict__ Of,
                                               uint16_t* __restrict__ Oh,
                                               uint16_t* __restrict__ Ol) {
  const int mf = blockIdx.x;  // 0..15
  const int tid = threadIdx.x;
  const int w = tid >> 6, l = tid & 63, l15 = l & 15, quad = l >> 4;
  const int ns = w * 32;
  f32x4 acc[2];
  acc[0] = {0.f, 0.f, 0.f, 0.f};
  acc[1] = {0.f, 0.f, 0.f, 0.f};

#pragma unroll
  for (int ks = 0; ks < 8; ++ks) {
    const float* ap = Af + (size_t)(mf * 16 + l15) * 256 + ks * 32 + quad * 8;
    f32x4 f0 = *reinterpret_cast<const f32x4*>(ap);
    f32x4 f1 = *reinterpret_cast<const f32x4*>(ap + 4);
    float fv[8] = {f0[0], f0[1], f0[2], f0[3], f1[0], f1[1], f1[2], f1[3]};
    short8 ah, al8;
    split8(fv, ah, al8);
#pragma unroll
    for (int nf = 0; nf < 2; ++nf) {
      const int off = (ns + nf * 16 + l15) * 256 + ks * 32 + quad * 8;
      short8 bhf = *reinterpret_cast<const short8*>(Bh + off);
      short8 blf = *reinterpret_cast<const short8*>(Bl + off);
      acc[nf] = MFMA16(ah, bhf, acc[nf]);
      acc[nf] = MFMA16(al8, bhf, acc[nf]);
      acc[nf] = MFMA16(ah, blf, acc[nf]);
    }
  }
#pragma unroll
  for (int nf = 0; nf < 2; ++nf)
#pragma unroll
    for (int r = 0; r < 4; ++r) {
      int row = mf * 16 + quad * 4 + r;
      int col = ns + nf * 16 + l15;
      float v = acc[nf][r];
      Of[(size_t)row * 256 + col] = v;
      uint16_t hb = f2bf(v);
      Oh[(size_t)col * 256 + row] = hb;
      Ol[(size_t)col * 256 + row] = f2bf(v - bf2f(hb));
    }
}

// ---------------- launch ----------------
extern "C" void kernel_launch(void* const* d_in, const int* in_sizes, int n_in,
                              void* d_out, int out_size, void* d_ws, size_t ws_size,
                              hipStream_t stream) {
  (void)in_sizes; (void)n_in; (void)out_size; (void)ws_size;
  const float* x0 = (const float*)d_in[0];
  const float* I  = (const float*)d_in[1];
  const float* eW = (const float*)d_in[2];
  const float* Wi = (const float*)d_in[3];
  float* out = (float*)d_out;
  char* ws = (char*)d_ws;

  float*    M1f = (float*)(ws + WS_M1F);
  uint16_t* M1h = (uint16_t*)(ws + WS_M1_HI);
  uint16_t* M1l = (uint16_t*)(ws + WS_M1_LO);
  float*    M2f = (float*)(ws + WS_M2F);
  uint16_t* M2h = (uint16_t*)(ws + WS_M2_HI);
  uint16_t* M2l = (uint16_t*)(ws + WS_M2_LO);
  float*    M3f = (float*)(ws + WS_M3F);
  uint16_t* M3h = (uint16_t*)(ws + WS_M3_HI);
  uint16_t* M3l = (uint16_t*)(ws + WS_M3_LO);
  float*    S   = (float*)(ws + WS_S);

  k_u<<<256, 512, 0, stream>>>(I, Wi, out);
  // M-power chain (Abar=eW^T): A^2 -> A^4 -> A^8 -> A^16(M1) -> A^32(M2) -> A^48(M3)
  k_mm256A<<<16, 512, 0, stream>>>(eW, M3f, M3h, M3l);            // A^2
  k_mm256<<<16, 512, 0, stream>>>(M3f, M3h, M3l, M2f, M2h, M2l);  // A^4
  k_mm256<<<16, 512, 0, stream>>>(M2f, M2h, M2l, M3f, M3h, M3l);  // A^8
  k_mm256<<<16, 512, 0, stream>>>(M3f, M3h, M3l, M1f, M1h, M1l);  // A^16 -> M1
  k_mm256<<<16, 512, 0, stream>>>(M1f, M1h, M1l, M2f, M2h, M2l);  // A^32 -> M2
  k_mm256<<<16, 512, 0, stream>>>(M2f, M1h, M1l, M3f, M3h, M3l);  // A^48 -> M3
  k_scan<<<512, 512, 0, stream>>>(1, eW, out, x0, S,
                                  M1h, M1l, M2h, M2l, M3h, M3l);
  k_scan<<<512, 512, 0, stream>>>(2, eW, out, x0, S,
                                  M1h, M1l, M2h, M2l, M3h, M3l);
}

// Round 14
// 282.832 us; speedup vs baseline: 2.7463x; 2.7463x over previous
//
#include <hip/hip_runtime.h>
#include <stdint.h>
#include <stddef.h>

// ISNNet: x[:,0]=x0; x[:,t] = x[:,t-1] @ eW.T + I[:,t-1] @ W_inv_eW.T
// B=64, T=2048, D=256.  3-term compensated bf16 MFMA throughout.
// Round 14: revert to the round-10 kernel (verified 282us best).
// r12 strength-reduction (neutral-negative) and r13 8-wave scan (register
// starvation -> scratch storm) both discarded.
// Structure: 32x32x16-MFMA k_u; CHUNK=32 16-wave scans (only reg-feasible
// shape: 64-reg frags within the 128-reg/wave unified budget at 4 waves/EU);
// fused J=2 boundary in scan pass 2; 6-stage mm chain; 9 dispatches.

#define BATCH 64
#define TLEN 2048
#define DDIM 256
#define CHUNK 32
#define NCHUNK 64

typedef __attribute__((ext_vector_type(8))) short short8;
typedef __attribute__((ext_vector_type(4))) float f32x4;
typedef __attribute__((ext_vector_type(16))) float f32x16;

#define MFMA16(a, b, c) __builtin_amdgcn_mfma_f32_16x16x32_bf16((a), (b), (c), 0, 0, 0)
#define MFMA32(a, b, c) __builtin_amdgcn_mfma_f32_32x32x16_bf16((a), (b), (c), 0, 0, 0)
#define PIN8(x) asm volatile("" : "+v"(x))

__device__ __forceinline__ uint16_t f2bf(float f) {
  union { float f; uint32_t u; } v; v.f = f;
  return (uint16_t)((v.u + 0x7fffu + ((v.u >> 16) & 1u)) >> 16);  // RNE
}
__device__ __forceinline__ float bf2f(uint16_t h) {
  union { uint32_t u; float f; } v; v.u = ((uint32_t)h) << 16;
  return v.f;
}

__device__ __forceinline__ void split8(const float* fv, short8& hi, short8& lo) {
#pragma unroll
  for (int j = 0; j < 8; ++j) {
    uint16_t hb = f2bf(fv[j]);
    hi[j] = (short)hb;
    lo[j] = (short)f2bf(fv[j] - bf2f(hb));
  }
}

// 16-row swizzle (scan state tiles)
__device__ __forceinline__ uint32_t swz(int row) {
  return ((uint32_t)((row & 7) << 4)) ^ ((uint32_t)(((row >> 3) & 1) << 7));
}
// 32-row swizzle (k_u I-tiles)
__device__ __forceinline__ uint32_t swz32(int row) {
  return ((uint32_t)((row & 7) << 4)) ^ ((uint32_t)(((row >> 3) & 3) << 7));
}

// raw barrier: waits LDS ops but NOT outstanding global loads
__device__ __forceinline__ void wg_barrier() {
  __builtin_amdgcn_sched_barrier(0);
  asm volatile("s_waitcnt lgkmcnt(0)" ::: "memory");
  __builtin_amdgcn_s_barrier();
  asm volatile("" ::: "memory");
  __builtin_amdgcn_sched_barrier(0);
}

// ---------------- workspace layout (bytes) ----------------
#define WS_M1F    (0)            // f32 [256][256]
#define WS_M1_HI  (256 * 1024)
#define WS_M1_LO  (384 * 1024)
#define WS_M2F    (512 * 1024)
#define WS_M2_HI  (768 * 1024)
#define WS_M2_LO  (896 * 1024)
#define WS_M3F    (1024 * 1024)
#define WS_M3_HI  (1280 * 1024)
#define WS_M3_LO  (1408 * 1024)
#define WS_S      (2560 * 1024)  // f32 [64][64][256] = 4MB

// ---------------- k_u: u = I @ Wi^T -> d_out at time t+1 (32x32x16 MFMA) ----
// 8 waves x (32 rows x 32 cols); 256 WGs x 16 tiles of 32 t-rows; LDS dbuf.
__global__ __launch_bounds__(512, 1) void k_u(const float* __restrict__ I,
                                              const float* __restrict__ Wi,
                                              float* __restrict__ out) {
  const int tid = threadIdx.x;
  const int w = tid >> 6, l = tid & 63, l31 = l & 31, half = l >> 5;
  const int ns = w * 32;  // 32 cols per wave
  __shared__ __align__(16) uint16_t sIh[2][8192];  // 32 x 256 bf16, swizzled
  __shared__ __align__(16) uint16_t sIl[2][8192];

  // Wb fragments: col = ns+l31, k = ks*16 + half*8 .. +8  (128 regs, pinned)
  short8 bh[16], bl[16];
#pragma unroll
  for (int ks = 0; ks < 16; ++ks) {
    const float* wp = Wi + (size_t)(ns + l31) * 256 + ks * 16 + half * 8;
    f32x4 f0 = *reinterpret_cast<const f32x4*>(wp);
    f32x4 f1 = *reinterpret_cast<const f32x4*>(wp + 4);
    float fv[8] = {f0[0], f0[1], f0[2], f0[3], f1[0], f1[1], f1[2], f1[3]};
    split8(fv, bh[ks], bl[ks]);
    PIN8(bh[ks]);
    PIN8(bl[ks]);
  }

  const int srow = tid >> 4;        // 0..31 (staging row)
  const int sc0 = (tid & 15) * 16;  // 0..240 (staging col base, 16 f32)
  const uint32_t wb0 = ((uint32_t)(srow * 512 + sc0 * 2)) ^ swz32(srow);
  const uint32_t wb1 = ((uint32_t)(srow * 512 + sc0 * 2 + 16)) ^ swz32(srow);

  f32x4 ra[4], rb[4];
  auto loadI = [&](int tl, f32x4 (&dst)[4]) {
    const int b = tl >> 6, tt = tl & 63;
    const float* src = I + ((size_t)b * TLEN + tt * 32 + srow) * DDIM + sc0;
#pragma unroll
    for (int j = 0; j < 4; ++j)
      dst[j] = *reinterpret_cast<const f32x4*>(src + j * 4);
  };

  auto do_tile = [&](int tl, f32x4 (&cur)[4], int q, bool pre) {
    short8 hi[2], lo[2];
#pragma unroll
    for (int h2 = 0; h2 < 2; ++h2) {
      float fv[8] = {cur[h2 * 2][0], cur[h2 * 2][1], cur[h2 * 2][2], cur[h2 * 2][3],
                     cur[h2 * 2 + 1][0], cur[h2 * 2 + 1][1], cur[h2 * 2 + 1][2], cur[h2 * 2 + 1][3]};
      split8(fv, hi[h2], lo[h2]);
    }
    if (pre) loadI(tl + 512, cur);   // reload same buffer for tile tl+2
    *reinterpret_cast<short8*>(reinterpret_cast<char*>(sIh[q]) + wb0) = hi[0];
    *reinterpret_cast<short8*>(reinterpret_cast<char*>(sIh[q]) + wb1) = hi[1];
    *reinterpret_cast<short8*>(reinterpret_cast<char*>(sIl[q]) + wb0) = lo[0];
    *reinterpret_cast<short8*>(reinterpret_cast<char*>(sIl[q]) + wb1) = lo[1];
    wg_barrier();                    // writes of buf q visible; buf q^1 free
    const int b = tl >> 6, tt = tl & 63;
    f32x16 acc;
#pragma unroll
    for (int j = 0; j < 16; ++j) acc[j] = 0.f;
    __builtin_amdgcn_s_setprio(1);
#pragma unroll
    for (int ks = 0; ks < 16; ++ks) {
      uint32_t rbyte = ((uint32_t)(l31 * 512 + ks * 32 + half * 16)) ^ swz32(l31);
      short8 ih = *reinterpret_cast<const short8*>((const char*)sIh[q] + rbyte);
      short8 il = *reinterpret_cast<const short8*>((const char*)sIl[q] + rbyte);
      acc = MFMA32(ih, bh[ks], acc);
      acc = MFMA32(il, bh[ks], acc);
      acc = MFMA32(ih, bl[ks], acc);
    }
    __builtin_amdgcn_s_setprio(0);
#pragma unroll
    for (int r = 0; r < 16; ++r) {
      int row = (r & 3) + 8 * (r >> 2) + 4 * half;
      int trow = tt * 32 + row;
      if (trow <= TLEN - 2) {  // u_t lives at location t+1; t <= 2046
        out[((size_t)b * TLEN + trow + 1) * DDIM + ns + l31] = acc[r];
      }
    }
  };

  const int tl0 = blockIdx.x;  // 16 tiles: tl0 + k*256 (4096 tiles of 32 rows)
  loadI(tl0, ra);
  loadI(tl0 + 256, rb);
#pragma unroll 1
  for (int it = 0; it < 16; it += 2) {
    do_tile(tl0 + it * 256, ra, 0, it + 2 < 16);
    do_tile(tl0 + (it + 1) * 256, rb, 1, it + 3 < 16);
  }
}

// ---------------- k_scan: in-chunk recurrence (CHUNK=32), 16-wave WGs -------
// pass 2 init computes Y_c = T_c + T_{c-1}@M1 + T_{c-2}@M2 inline (fused bnd).
__global__ __launch_bounds__(1024) void k_scan(const int pass,
                                               const float* __restrict__ eW,
                                               float* __restrict__ xu,  // d_out: u in (shifted), x out
                                               const float* __restrict__ x0,
                                               float* __restrict__ S,
                                               const uint16_t* __restrict__ M1h,
                                               const uint16_t* __restrict__ M1l,
                                               const uint16_t* __restrict__ M2h,
                                               const uint16_t* __restrict__ M2l) {
  const int tid = threadIdx.x;
  const int w = tid >> 6, l = tid & 63, l15 = l & 15, quad = l >> 4;
  const int ns = w * 16;  // 16 cols per wave
  const int c = blockIdx.x >> 2;
  const int rg = blockIdx.x & 3;
  __shared__ __align__(16) uint16_t sh[2][4096];
  __shared__ __align__(16) uint16_t sl[2][4096];

  const int t0 = c * CHUNK;
  const int nsteps = (t0 + CHUNK <= TLEN - 1) ? CHUNK : (TLEN - 1 - t0);

  float u0[4], u1[4], u2[4], u3[4], fin[4];
#pragma unroll
  for (int j = 0; j < 4; ++j) { u0[j] = 0.f; u1[j] = 0.f; u2[j] = 0.f; u3[j] = 0.f; fin[j] = 0.f; }

  auto issue_u = [&](int i, float (&dst)[4]) {
    if (i > nsteps) return;
#pragma unroll
    for (int r = 0; r < 4; ++r) {
      int b = rg * 16 + quad * 4 + r;
      dst[r] = xu[((size_t)b * TLEN + t0 + i) * DDIM + ns + l15];
    }
  };
  // fire the first 4 steps' u loads before anything else
  issue_u(1, u0);
  issue_u(2, u1);
  issue_u(3, u2);
  issue_u(4, u3);

  // A fragments: per-wave 16-col slice, split from f32 eW, pinned
  short8 fAh[8], fAl[8];
#pragma unroll
  for (int ks = 0; ks < 8; ++ks) {
    const float* ap = eW + (size_t)(ns + l15) * 256 + ks * 32 + quad * 8;
    f32x4 f0 = *reinterpret_cast<const f32x4*>(ap);
    f32x4 f1 = *reinterpret_cast<const f32x4*>(ap + 4);
    float fv[8] = {f0[0], f0[1], f0[2], f0[3], f1[0], f1[1], f1[2], f1[3]};
    split8(fv, fAh[ks], fAl[ks]);
    PIN8(fAh[ks]);
    PIN8(fAl[ks]);
  }

  // init state (buf 0)
  if (pass == 1) {
    for (int i = tid; i < 4096; i += 1024) {
      int row = i >> 8, k = i & 255;
      uint32_t byte = ((uint32_t)(row * 512 + k * 2)) ^ swz(row);
      *(uint16_t*)((char*)sh[0] + byte) = 0;
      *(uint16_t*)((char*)sl[0] + byte) = 0;
    }
  } else {
    // fused k_bnd: Y = T_c + T_{c-1}@M1 + T_{c-2}@M2 for this WG's rows/cols
    f32x4 yacc;
    {
      const float* Tc = (c == 0) ? x0 : (S + (size_t)(c - 1) * 64 * 256);
#pragma unroll
      for (int r = 0; r < 4; ++r)
        yacc[r] = Tc[(size_t)(rg * 16 + quad * 4 + r) * 256 + ns + l15];
    }
#pragma unroll 1
    for (int j = 1; j <= 2; ++j) {
      int k = c - j;
      if (k < 0) break;
      const float* Tp = (k == 0) ? x0 : (S + (size_t)(k - 1) * 64 * 256);
      const uint16_t* Bh = (j == 1) ? M1h : M2h;
      const uint16_t* Bl = (j == 1) ? M1l : M2l;
#pragma unroll
      for (int ks = 0; ks < 8; ++ks) {
        const float* ap = Tp + (size_t)(rg * 16 + l15) * 256 + ks * 32 + quad * 8;
        f32x4 f0 = *reinterpret_cast<const f32x4*>(ap);
        f32x4 f1 = *reinterpret_cast<const f32x4*>(ap + 4);
        float fv[8] = {f0[0], f0[1], f0[2], f0[3], f1[0], f1[1], f1[2], f1[3]};
        short8 ah, al8;
        split8(fv, ah, al8);
        const int off = (ns + l15) * 256 + ks * 32 + quad * 8;
        short8 bhf = *reinterpret_cast<const short8*>(Bh + off);
        short8 blf = *reinterpret_cast<const short8*>(Bl + off);
        yacc = MFMA16(ah, bhf, yacc);
        yacc = MFMA16(al8, bhf, yacc);
        yacc = MFMA16(ah, blf, yacc);
      }
    }
#pragma unroll
    for (int r = 0; r < 4; ++r) {
      int row = quad * 4 + r, col = ns + l15;
      float v = yacc[r];
      if (c == 0) xu[((size_t)(rg * 16 + row) * TLEN) * DDIM + col] = v;  // x[:,0,:]
      uint16_t hb = f2bf(v);
      uint16_t lb = f2bf(v - bf2f(hb));
      uint32_t byte = ((uint32_t)(row * 512 + col * 2)) ^ swz(row);
      *(uint16_t*)((char*)sh[0] + byte) = hb;
      *(uint16_t*)((char*)sl[0] + byte) = lb;
    }
  }
  wg_barrier();  // no vmcnt drain: u prefetches stay in flight

  int p = 0;
  auto step = [&](int i, float (&ucur)[4]) {
    f32x4 acc = {0.f, 0.f, 0.f, 0.f};
    __builtin_amdgcn_s_setprio(1);
#pragma unroll
    for (int ks = 0; ks < 8; ++ks) {
      uint32_t byte = ((uint32_t)(l15 * 512 + ks * 64 + quad * 16)) ^ swz(l15);
      short8 xh = *reinterpret_cast<const short8*>((const char*)sh[p] + byte);
      short8 xl = *reinterpret_cast<const short8*>((const char*)sl[p] + byte);
      acc = MFMA16(xh, fAh[ks], acc);
      acc = MFMA16(xl, fAh[ks], acc);
      acc = MFMA16(xh, fAl[ks], acc);
    }
    __builtin_amdgcn_s_setprio(0);
#pragma unroll
    for (int r = 0; r < 4; ++r) fin[r] = acc[r] + ucur[r];
    issue_u(i + 4, ucur);  // refill this buffer for step i+4
    if (pass == 2) {
#pragma unroll
      for (int r = 0; r < 4; ++r) {
        int b = rg * 16 + quad * 4 + r;
        xu[((size_t)b * TLEN + t0 + i) * DDIM + ns + l15] = fin[r];
      }
    }
    if (i < nsteps) {
#pragma unroll
      for (int r = 0; r < 4; ++r) {
        int row = quad * 4 + r, col = ns + l15;
        float v = fin[r];
        uint16_t hb = f2bf(v);
        uint16_t lb = f2bf(v - bf2f(hb));
        uint32_t byte = ((uint32_t)(row * 512 + col * 2)) ^ swz(row);
        *(uint16_t*)((char*)sh[p ^ 1] + byte) = hb;
        *(uint16_t*)((char*)sl[p ^ 1] + byte) = lb;
      }
      wg_barrier();
      p ^= 1;
    }
  };

  int i = 1;
  for (; i + 3 <= nsteps; i += 4) {
    step(i, u0);
    step(i + 1, u1);
    step(i + 2, u2);
    step(i + 3, u3);
  }
  if (i <= nsteps) { step(i, u0); ++i; }
  if (i <= nsteps) { step(i, u1); ++i; }
  if (i <= nsteps) { step(i, u2); ++i; }

  if (pass == 1) {
#pragma unroll
    for (int r = 0; r < 4; ++r) {
      int row = quad * 4 + r, col = ns + l15;
      S[((size_t)c * 64 + rg * 16 + row) * DDIM + col] = fin[r];
    }
  }
}

// ---------------- k_mm256A: OUT = Abar @ Abar from raw eW (stage 1) ----------
__global__ __launch_bounds__(512) void k_mm256A(const float* __restrict__ eW,
                                                float* __restrict__ Of,
                                                uint16_t* __restrict__ Oh,
                                                uint16_t* __restrict__ Ol) {
  const int mf = blockIdx.x;  // 0..15
  const int tid = threadIdx.x;
  const int w = tid >> 6, l = tid & 63, l15 = l & 15, quad = l >> 4;
  const int ns = w * 32;
  f32x4 acc[2];
  acc[0] = {0.f, 0.f, 0.f, 0.f};
  acc[1] = {0.f, 0.f, 0.f, 0.f};

#pragma unroll
  for (int ks = 0; ks < 8; ++ks) {
    float fv[8];
#pragma unroll
    for (int j = 0; j < 8; ++j)
      fv[j] = eW[(size_t)(ks * 32 + quad * 8 + j) * 256 + mf * 16 + l15];
    short8 ah, al8;
    split8(fv, ah, al8);
#pragma unroll
    for (int nf = 0; nf < 2; ++nf) {
      const float* bp = eW + (size_t)(ns + nf * 16 + l15) * 256 + ks * 32 + quad * 8;
      f32x4 b0 = *reinterpret_cast<const f32x4*>(bp);
      f32x4 b1 = *reinterpret_cast<const f32x4*>(bp + 4);
      float bv[8] = {b0[0], b0[1], b0[2], b0[3], b1[0], b1[1], b1[2], b1[3]};
      short8 bhf, blf;
      split8(bv, bhf, blf);
      acc[nf] = MFMA16(ah, bhf, acc[nf]);
      acc[nf] = MFMA16(al8, bhf, acc[nf]);
      acc[nf] = MFMA16(ah, blf, acc[nf]);
    }
  }
#pragma unroll
  for (int nf = 0; nf < 2; ++nf)
#pragma unroll
    for (int r = 0; r < 4; ++r) {
      int row = mf * 16 + quad * 4 + r;
      int col = ns + nf * 16 + l15;
      float v = acc[nf][r];
      Of[(size_t)row * 256 + col] = v;
      uint16_t hb = f2bf(v);
      Oh[(size_t)col * 256 + row] = hb;
      Ol[(size_t)col * 256 + row] = f2bf(v - bf2f(hb));
    }
}

// ---------------- k_mm256: OUT = Af @ B, 16 WGs (stages 2+) ----------------
__global__ __launch_bounds__(512) void k_mm256(const float* __restrict__ Af,
                                               const uint16_t* __restrict__ Bh,
                                               const uint16_t* __restrict__ Bl,
                                               float* __restrict__ Of,
                                               uint16_t* __restrict__ Oh,
                                               uint16_t* __restrict__ Ol) {
  const int mf = blockIdx.x;  // 0..15
  const int tid = threadIdx.x;
  const int w = tid >> 6, l = tid & 63, l15 = l & 15, quad = l >> 4;
  const int ns = w * 32;
  f32x4 acc[2];
  acc[0] = {0.f, 0.f, 0.f, 0.f};
  acc[1] = {0.f, 0.f, 0.f, 0.f};

#pragma unroll
  for (int ks = 0; ks < 8; ++ks) {
    const float* ap = Af + (size_t)(mf * 16 + l15) * 256 + ks * 32 + quad * 8;
    f32x4 f0 = *reinterpret_cast<const f32x4*>(ap);
    f32x4 f1 = *reinterpret_cast<const f32x4*>(ap + 4);
    float fv[8] = {f0[0], f0[1], f0[2], f0[3], f1[0], f1[1], f1[2], f1[3]};
    short8 ah, al8;
    split8(fv, ah, al8);
#pragma unroll
    for (int nf = 0; nf < 2; ++nf) {
      const int off = (ns + nf * 16 + l15) * 256 + ks * 32 + quad * 8;
      short8 bhf = *reinterpret_cast<const short8*>(Bh + off);
      short8 blf = *reinterpret_cast<const short8*>(Bl + off);
      acc[nf] = MFMA16(ah, bhf, acc[nf]);
      acc[nf] = MFMA16(al8, bhf, acc[nf]);
      acc[nf] = MFMA16(ah, blf, acc[nf]);
    }
  }
#pragma unroll
  for (int nf = 0; nf < 2; ++nf)
#pragma unroll
    for (int r = 0; r < 4; ++r) {
      int row = mf * 16 + quad * 4 + r;
      int col = ns + nf * 16 + l15;
      float v = acc[nf][r];
      Of[(size_t)row * 256 + col] = v;
      uint16_t hb = f2bf(v);
      Oh[(size_t)col * 256 + row] = hb;
      Ol[(size_t)col * 256 + row] = f2bf(v - bf2f(hb));
    }
}

// ---------------- launch ----------------
extern "C" void kernel_launch(void* const* d_in, const int* in_sizes, int n_in,
                              void* d_out, int out_size, void* d_ws, size_t ws_size,
                              hipStream_t stream) {
  (void)in_sizes; (void)n_in; (void)out_size; (void)ws_size;
  const float* x0 = (const float*)d_in[0];
  const float* I  = (const float*)d_in[1];
  const float* eW = (const float*)d_in[2];
  const float* Wi = (const float*)d_in[3];
  float* out = (float*)d_out;
  char* ws = (char*)d_ws;

  float*    M1f = (float*)(ws + WS_M1F);
  uint16_t* M1h = (uint16_t*)(ws + WS_M1_HI);
  uint16_t* M1l = (uint16_t*)(ws + WS_M1_LO);
  float*    M2f = (float*)(ws + WS_M2F);
  uint16_t* M2h = (uint16_t*)(ws + WS_M2_HI);
  uint16_t* M2l = (uint16_t*)(ws + WS_M2_LO);
  float*    M3f = (float*)(ws + WS_M3F);
  uint16_t* M3h = (uint16_t*)(ws + WS_M3_HI);
  uint16_t* M3l = (uint16_t*)(ws + WS_M3_LO);
  float*    S   = (float*)(ws + WS_S);

  k_u<<<256, 512, 0, stream>>>(I, Wi, out);
  // M-power chain (Abar=eW^T): A^2 -> A^4 -> A^8 -> A^16 -> A^32(M1) -> A^64(M2)
  k_mm256A<<<16, 512, 0, stream>>>(eW, M3f, M3h, M3l);            // A^2
  k_mm256<<<16, 512, 0, stream>>>(M3f, M3h, M3l, M2f, M2h, M2l);  // A^4
  k_mm256<<<16, 512, 0, stream>>>(M2f, M2h, M2l, M3f, M3h, M3l);  // A^8
  k_mm256<<<16, 512, 0, stream>>>(M3f, M3h, M3l, M2f, M2h, M2l);  // A^16
  k_mm256<<<16, 512, 0, stream>>>(M2f, M2h, M2l, M1f, M1h, M1l);  // A^32 -> M1
  k_mm256<<<16, 512, 0, stream>>>(M1f, M1h, M1l, M2f, M2h, M2l);  // A^64 -> M2
  k_scan<<<256, 1024, 0, stream>>>(1, eW, out, x0, S, M1h, M1l, M2h, M2l);
  k_scan<<<256, 1024, 0, stream>>>(2, eW, out, x0, S, M1h, M1l, M2h, M2l);
}